// Round 2
// baseline (518.388 us; speedup 1.0000x reference)
//
#include <hip/hip_runtime.h>

#define PP 8732
#define NB 20
#define NC 21
#define BTS 1024
#define NWS 16
#define NCH 9           // ceil(PP/1024)

__device__ __forceinline__ float sl1(float d){
  float a = fabsf(d);
  return a < 1.0f ? 0.5f*a*a : a - 0.5f;
}

// Full 64-lane max via DPP (VALU pipe only); result valid in lane 63, broadcast
// to all lanes through readlane. bound_ctrl=1 injects 0.0 at row edges -- harmless
// here since the true max is always >= 0 (IoU >= 0 and lane 0 is always valid).
__device__ __forceinline__ float wave_max64(float x){
  int t;
  t = __builtin_amdgcn_update_dpp(0, __float_as_int(x), 0x111, 0xF, 0xF, true); x = fmaxf(x, __int_as_float(t));
  t = __builtin_amdgcn_update_dpp(0, __float_as_int(x), 0x112, 0xF, 0xF, true); x = fmaxf(x, __int_as_float(t));
  t = __builtin_amdgcn_update_dpp(0, __float_as_int(x), 0x114, 0xF, 0xF, true); x = fmaxf(x, __int_as_float(t));
  t = __builtin_amdgcn_update_dpp(0, __float_as_int(x), 0x118, 0xF, 0xF, true); x = fmaxf(x, __int_as_float(t));
  t = __builtin_amdgcn_update_dpp(0, __float_as_int(x), 0x142, 0xF, 0xF, true); x = fmaxf(x, __int_as_float(t));
  t = __builtin_amdgcn_update_dpp(0, __float_as_int(x), 0x143, 0xF, 0xF, true); x = fmaxf(x, __int_as_float(t));
  return __int_as_float(__builtin_amdgcn_readlane(__float_as_int(x), 63));
}

// Full 64-lane sum via DPP (VALU pipe only); result valid in lane 63 only.
// bound_ctrl=1 injects 0 (identity for add) -> exact for any input.
__device__ __forceinline__ int wave_sum64_lane63(int x){
  x += __builtin_amdgcn_update_dpp(0, x, 0x111, 0xF, 0xF, true);
  x += __builtin_amdgcn_update_dpp(0, x, 0x112, 0xF, 0xF, true);
  x += __builtin_amdgcn_update_dpp(0, x, 0x114, 0xF, 0xF, true);
  x += __builtin_amdgcn_update_dpp(0, x, 0x118, 0xF, 0xF, true);
  x += __builtin_amdgcn_update_dpp(0, x, 0x142, 0xF, 0xF, true);
  x += __builtin_amdgcn_update_dpp(0, x, 0x143, 0xF, 0xF, true);
  return x;
}

// Fused: phase 1 = match + logsumexp per (b, chunk); last-finishing chunk block
// of each row runs phase 2 (scatter + positive losses + top-k) inline for that
// row. Removes the device-wide kernel boundary: row b's selection overlaps other
// rows' matching. conf goes direct to registers (no LDS on the phase-1 path).
extern "C" __global__ void __launch_bounds__(BTS)
mb_fused(const float* __restrict__ loc_data,
         const float* __restrict__ conf_data,
         const float* __restrict__ priors,
         const float* __restrict__ targets,
         float* __restrict__ rankneg,
         unsigned char* __restrict__ meta,
         unsigned long long* __restrict__ keys2,
         int* __restrict__ done,
         float* __restrict__ rowres, int* __restrict__ ticket,
         float* __restrict__ out, int Bn)
{
  const int b = blockIdx.x, chunk = blockIdx.y;
  const int tid = threadIdx.x, lane = tid & 63, wid = tid >> 6;
  const int q0 = chunk*BTS + wid*64;
  const int cnt = (q0 < PP) ? ((PP - q0 < 64) ? (PP - q0) : 64) : 0;

  __shared__ unsigned long long s_keys[NWS][NB];
  __shared__ __align__(16) unsigned int s_meta4[PP/4];   // 8732 B
  __shared__ float4 s_tr4[NB];
  __shared__ float s_lab[NB];
  __shared__ int   s_bp[NB];
  __shared__ int   s_tot[32];
  __shared__ float s_fa[NWS], s_fb[NWS], s_fc[NWS];
  __shared__ int   s_ia[NWS];
  __shared__ float s_rowll, s_rowpc;
  __shared__ int   s_npos, s_go, s_last;
  unsigned char* s_meta = (unsigned char*)s_meta4;

  // ---------------- phase 1: match + LSE for this chunk ----------------
  unsigned long long mykey = 0ULL;     // lane n holds truth n's wave-winner key

  if (cnt > 0){
    const bool valid = (lane < cnt);
    const int p  = q0 + lane;
    const int pl = valid ? p : q0;

    // truths in lanes 0..19 (per wave; L1-hot), broadcast per-n via readlane
    float tx=0.f, ty=0.f, tz=0.f, tw=0.f;
    if (lane < NB){
      const float* tp = targets + ((long)b*NB + lane)*5;
      tx = tp[0]; ty = tp[1]; tz = tp[2]; tw = tp[3];
    }
    float4 pr = reinterpret_cast<const float4*>(priors)[pl];

    // conf direct to registers: 5x dwordx4 + 1 dword per lane (84 B window,
    // wave covers contiguous 5376 B -> all cache-line bytes consumed; latency
    // hides under the 20-truth VALU loop below).
    const float* cb = conf_data + ((long)b*PP + pl)*NC;
    const float4* cb4 = reinterpret_cast<const float4*>(cb);   // 4B-aligned ok (dwordx4)
    float4 ca0 = cb4[0], ca1 = cb4[1], ca2 = cb4[2], ca3 = cb4[3], ca4 = cb4[4];
    float c20 = cb[20];

    float bx1 = pr.x - pr.z*0.5f, by1 = pr.y - pr.w*0.5f;
    float bx2 = pr.x + pr.z*0.5f, by2 = pr.y + pr.w*0.5f;
    float area_b = (bx2-bx1)*(by2-by1);
    float area_a = (tz-tx)*(tw-ty);                   // valid in lanes 0..19
    float bestov = -1.0f; int bestn = 0;

    #pragma unroll 4
    for (int n=0;n<NB;n++){
      float t_x = __int_as_float(__builtin_amdgcn_readlane(__float_as_int(tx), n));
      float t_y = __int_as_float(__builtin_amdgcn_readlane(__float_as_int(ty), n));
      float t_z = __int_as_float(__builtin_amdgcn_readlane(__float_as_int(tz), n));
      float t_w = __int_as_float(__builtin_amdgcn_readlane(__float_as_int(tw), n));
      float aa  = __int_as_float(__builtin_amdgcn_readlane(__float_as_int(area_a), n));
      float lx=fmaxf(t_x,bx1), ly=fmaxf(t_y,by1);
      float rx=fminf(t_z,bx2), ry=fminf(t_w,by2);
      float iw=fmaxf(rx-lx,0.f), ih=fmaxf(ry-ly,0.f);
      float inter = iw*ih;
      float iou = inter * __builtin_amdgcn_rcpf(aa + area_b - inter);
      if (iou > bestov){ bestov=iou; bestn=n; }          // strict > = first-max over n

      // per-truth wave argmax: DPP max + ballot; tie -> lowest lane = min p.
      // wmax bits == winner's iou bits (all +normal/+0); key built on SALU.
      float iouv = valid ? iou : -1.0f;
      float wmax = wave_max64(iouv);
      unsigned long long mk = __ballot(valid && (iou == wmax));   // nonzero: lane0 valid
      int wlane = __ffsll((long long)mk) - 1;
      unsigned long long key = ((unsigned long long)__float_as_uint(wmax)<<32)
                             | (unsigned long long)(0xFFFFFFFFu - (unsigned)(q0 + wlane));
      if (lane == n) mykey = key;
    }

    // logsumexp entirely from registers
    float vv[NC] = {ca0.x,ca0.y,ca0.z,ca0.w, ca1.x,ca1.y,ca1.z,ca1.w,
                    ca2.x,ca2.y,ca2.z,ca2.w, ca3.x,ca3.y,ca3.z,ca3.w,
                    ca4.x,ca4.y,ca4.z,ca4.w, c20};
    float m = vv[0];
    #pragma unroll
    for (int c=1;c<NC;c++) m = fmaxf(m, vv[c]);
    float s = 0.f;
    #pragma unroll
    for (int c=0;c<NC;c++) s += __expf(vv[c]-m);
    float lse = __logf(s) + m;
    if (valid){
      rankneg[(long)b*PP + p] = lse - vv[0];
      meta[(long)b*PP + p] = (unsigned char)((bestn<<1) | (bestov >= 0.5f ? 1 : 0));
    }
  }
  if (lane < NB) s_keys[wid][lane] = mykey;         // cnt==0 waves write zeros

  __syncthreads();
  if (tid < NB){
    unsigned long long mx = s_keys[0][tid];
    #pragma unroll
    for (int w=1;w<NWS;w++) if (s_keys[w][tid] > mx) mx = s_keys[w][tid];
    keys2[((long)b*NCH + chunk)*NB + tid] = mx;
  }

  // release: all stores -> fence (each thread) -> barrier -> one atomic
  __threadfence();
  __syncthreads();
  if (tid == 0) s_go = (atomicAdd(&done[b], 1) == NCH-1) ? 1 : 0;
  __syncthreads();
  if (!s_go) return;                                 // not the last chunk of row b

  // ---------------- phase 2: selection for row b (last block only) ----------------
  __threadfence();                                   // acquire other chunks' stores

  // rank values straight to registers (values independent of overrides)
  const float4* rr = reinterpret_cast<const float4*>(rankneg + (long)b*PP);
  float4 rv0 = rr[tid];
  float4 rv1 = rr[tid+1024];
  float4 rv2 = (tid < PP/4-2048) ? rr[tid+2048] : make_float4(0.f,0.f,0.f,0.f);

  const unsigned int* mr = reinterpret_cast<const unsigned int*>(meta + (long)b*PP);
  for (int i=tid;i<PP/4;i+=BTS) s_meta4[i]=mr[i];
  if (tid < NB*5){
    int n = tid/5, k2 = tid-n*5;
    float vvv = targets[((long)b*NB+n)*5+k2];
    if (k2<4) ((float*)&s_tr4[n])[k2]=vvv; else s_lab[n]=vvv;
  }
  if (tid < NB){
    unsigned long long mx = 0ULL;
    #pragma unroll
    for (int c=0;c<NCH;c++){
      unsigned long long kk = keys2[((long)b*NCH + c)*NB + tid];
      if (kk > mx) mx = kk;
    }
    s_bp[tid] = (int)(0xFFFFFFFFu - (unsigned)(mx & 0xFFFFFFFFULL));
  }
  if (tid < 32) s_tot[tid] = 0;
  __syncthreads();

  // overrides, ascending n (max n wins on collisions), forced positive
  if (tid==0){
    for (int n=0;n<NB;n++) s_meta[s_bp[n]] = (unsigned char)((n<<1)|1);
  }
  __syncthreads();

  // mask positives to 0 in-register for the top-k (post-override meta)
  unsigned mm0 = s_meta4[tid];
  unsigned mm1 = s_meta4[tid+1024];
  unsigned mm2 = (tid < PP/4-2048) ? s_meta4[tid+2048] : 0u;
  if (mm0 & 0x00000001u) rv0.x = 0.f;
  if (mm0 & 0x00000100u) rv0.y = 0.f;
  if (mm0 & 0x00010000u) rv0.z = 0.f;
  if (mm0 & 0x01000000u) rv0.w = 0.f;
  if (mm1 & 0x00000001u) rv1.x = 0.f;
  if (mm1 & 0x00000100u) rv1.y = 0.f;
  if (mm1 & 0x00010000u) rv1.z = 0.f;
  if (mm1 & 0x01000000u) rv1.w = 0.f;
  if (mm2 & 0x00000001u) rv2.x = 0.f;
  if (mm2 & 0x00000100u) rv2.y = 0.f;
  if (mm2 & 0x00010000u) rv2.z = 0.f;
  if (mm2 & 0x01000000u) rv2.w = 0.f;

  // special case p==0 (clamped.at[0]): tid0-local registers
  int spec = 0; float delta = 0.f, val0 = 0.f;
  if (b==0 && tid==0 && !(mm0 & 1u)){
    float v0 = conf_data[0], v1 = conf_data[1];
    float r0 = rv0.x;                        // lse - v0 = true ce
    float r0p = r0 + v0 - v1;                // lse - v1 = ranking value
    delta = r0 - r0p;
    spec = 1;
    rv0.x = r0p; val0 = r0p;
  }

  // positive pass (identical iteration order; rankneg gathered from L2-hot global)
  float ll=0.f, pc=0.f; int np=0;
  for (int p=tid;p<PP;p+=BTS){
    int mt = s_meta[p];
    if (mt & 1){
      np++;
      int n = mt>>1;
      int ct = (int)s_lab[n] + 1;
      const float* cp = conf_data + ((long)b*PP+p)*NC;
      float v0 = cp[0], vct = cp[ct];
      pc += rankneg[(long)b*PP + p] + v0 - vct;   // lse - v[ct]
      float4 t = s_tr4[n];
      float4 prr = reinterpret_cast<const float4*>(priors)[p];
      float4 ld = reinterpret_cast<const float4*>(loc_data)[(long)b*PP+p];
      float g0 = ((t.x+t.z)*0.5f - prr.x)/(0.1f*prr.z);
      float g1 = ((t.y+t.w)*0.5f - prr.y)/(0.1f*prr.w);
      float g2 = __logf((t.z-t.x)/prr.z)/0.2f;
      float g3 = __logf((t.w-t.y)/prr.w)/0.2f;
      ll += sl1(ld.x-g0)+sl1(ld.y-g1)+sl1(ld.z-g2)+sl1(ld.w-g3);
    }
  }
  #pragma unroll
  for (int o=32;o;o>>=1){
    ll += __shfl_down(ll,o,64);
    pc += __shfl_down(pc,o,64);
    np += __shfl_down(np,o,64);
  }
  if (lane==0){ s_fa[wid]=ll; s_fb[wid]=pc; s_ia[wid]=np; }
  __syncthreads();
  if (tid==0){
    float a=0.f,c2=0.f; int ni=0;
    for (int w=0;w<NWS;w++){ a+=s_fa[w]; c2+=s_fb[w]; ni+=s_ia[w]; }
    s_rowll=a; s_rowpc=c2; s_npos=ni;
  }
  __syncthreads();
  const int num_pos = s_npos;
  int k = num_pos*3; if (k > PP-1) k = PP-1;

  float negsum = 0.f;
  if (k > 0){
    // k-th largest via binary search on float bits; DPP add + one LDS atomic per
    // wave + one broadcast read per iteration.
    unsigned lo=0u, hi=0x7f800000u;
    int it=0;
    while (lo < hi){
      unsigned mid = lo + ((hi - lo + 1u) >> 1);
      int c = (__float_as_uint(rv0.x)>=mid) + (__float_as_uint(rv0.y)>=mid)
            + (__float_as_uint(rv0.z)>=mid) + (__float_as_uint(rv0.w)>=mid)
            + (__float_as_uint(rv1.x)>=mid) + (__float_as_uint(rv1.y)>=mid)
            + (__float_as_uint(rv1.z)>=mid) + (__float_as_uint(rv1.w)>=mid)
            + (__float_as_uint(rv2.x)>=mid) + (__float_as_uint(rv2.y)>=mid)
            + (__float_as_uint(rv2.z)>=mid) + (__float_as_uint(rv2.w)>=mid);
      c = wave_sum64_lane63(c);
      if (lane==63) atomicAdd(&s_tot[it], c);
      __syncthreads();
      int tot = s_tot[it];
      if (tot >= k) lo = mid; else hi = mid - 1u;
      it++;                                   // <=31 iterations, s_tot[32] slots
    }
    const unsigned vstar = lo;

    int cg=0; float sg=0.f;
    #define ACC(x) if (__float_as_uint(x)>vstar){cg++;sg+=(x);}
    ACC(rv0.x) ACC(rv0.y) ACC(rv0.z) ACC(rv0.w)
    ACC(rv1.x) ACC(rv1.y) ACC(rv1.z) ACC(rv1.w)
    ACC(rv2.x) ACC(rv2.y) ACC(rv2.z) ACC(rv2.w)
    #undef ACC
    #pragma unroll
    for (int o=32;o;o>>=1){ cg += __shfl_down(cg,o,64); sg += __shfl_down(sg,o,64); }
    __syncthreads();
    if (lane==0){ s_ia[wid]=cg; s_fa[wid]=sg; }
    __syncthreads();
    if (tid==0){
      int cG=0; float sumG=0.f;
      for (int w=0;w<NWS;w++){ cG+=s_ia[w]; sumG+=s_fa[w]; }
      int tie = k - cG;                      // >=1; stable ties take lowest indices
      negsum = sumG + (float)tie * __uint_as_float(vstar);
      if (b==0 && spec && __float_as_uint(val0) >= vstar) negsum += delta;
    }
  }

  if (tid==0){
    rowres[b*4+0] = s_rowll;
    rowres[b*4+1] = s_rowpc + negsum;
    rowres[b*4+2] = (float)num_pos;
    __threadfence();
    int t = atomicAdd(ticket, 1);
    s_last = (t == Bn - 1) ? 1 : 0;
  }
  __syncthreads();

  if (s_last){
    __threadfence();
    float a0=0.f, a1=0.f, a2=0.f;
    for (int i=tid;i<Bn;i+=BTS){
      a0 += rowres[i*4+0]; a1 += rowres[i*4+1]; a2 += rowres[i*4+2];
    }
    #pragma unroll
    for (int o=32;o;o>>=1){
      a0 += __shfl_down(a0,o,64);
      a1 += __shfl_down(a1,o,64);
      a2 += __shfl_down(a2,o,64);
    }
    if (lane==0){ s_fa[wid]=a0; s_fb[wid]=a1; s_fc[wid]=a2; }
    __syncthreads();
    if (tid==0){
      float A0=0.f,A1=0.f,A2=0.f;
      for (int w=0;w<NWS;w++){ A0+=s_fa[w]; A1+=s_fb[w]; A2+=s_fc[w]; }
      out[0] = A0/A2;
      out[1] = A1/A2;
    }
  }
}

extern "C" void kernel_launch(void* const* d_in, const int* in_sizes, int n_in,
                              void* d_out, int out_size, void* d_ws, size_t ws_size,
                              hipStream_t stream) {
  const float* loc     = (const float*)d_in[0];
  const float* conf    = (const float*)d_in[1];
  const float* priors  = (const float*)d_in[2];
  const float* targets = (const float*)d_in[3];
  float* out = (float*)d_out;
  int B = in_sizes[0] / (PP*4);

  char* ws = (char*)d_ws;
  int*   ticket = (int*)ws;                       // [0,4)
  int*   done   = (int*)(ws + 64);                // [64, 64+4B) -- zeroed each launch
  float* rowres = (float*)(ws + 4096);
  size_t off_keys = 4096 + (size_t)((B*16 + 255) & ~255);
  unsigned long long* keys2 = (unsigned long long*)(ws + off_keys);
  size_t off_rank = (off_keys + (size_t)B*NCH*NB*8 + 255) & ~(size_t)255;
  float* rankneg = (float*)(ws + off_rank);
  unsigned char* metaa = (unsigned char*)(ws + off_rank + (size_t)B*PP*4);

  hipMemsetAsync(d_ws, 0, 4096, stream);          // ticket + done[]
  hipLaunchKernelGGL(mb_fused, dim3(B, NCH), dim3(BTS), 0, stream,
                     loc, conf, priors, targets, rankneg, metaa, keys2,
                     done, rowres, ticket, out, B);
}

// Round 3
// 237.088 us; speedup vs baseline: 2.1865x; 2.1865x over previous
//
#include <hip/hip_runtime.h>

#define PP 8732
#define NB 20
#define NC 21
#define BTS 1024
#define NWS 16
#define NPASS 9         // ceil(PP/1024)

__device__ __forceinline__ float sl1(float d){
  float a = fabsf(d);
  return a < 1.0f ? 0.5f*a*a : a - 0.5f;
}

// Full 64-lane max via DPP (VALU pipe only); result valid in lane 63, broadcast
// to all lanes through readlane. bound_ctrl=1 injects 0.0 at row edges -- harmless
// here since the true max is always >= 0 (IoU >= 0 and lane 0 is always valid).
__device__ __forceinline__ float wave_max64(float x){
  int t;
  t = __builtin_amdgcn_update_dpp(0, __float_as_int(x), 0x111, 0xF, 0xF, true); x = fmaxf(x, __int_as_float(t));
  t = __builtin_amdgcn_update_dpp(0, __float_as_int(x), 0x112, 0xF, 0xF, true); x = fmaxf(x, __int_as_float(t));
  t = __builtin_amdgcn_update_dpp(0, __float_as_int(x), 0x114, 0xF, 0xF, true); x = fmaxf(x, __int_as_float(t));
  t = __builtin_amdgcn_update_dpp(0, __float_as_int(x), 0x118, 0xF, 0xF, true); x = fmaxf(x, __int_as_float(t));
  t = __builtin_amdgcn_update_dpp(0, __float_as_int(x), 0x142, 0xF, 0xF, true); x = fmaxf(x, __int_as_float(t));
  t = __builtin_amdgcn_update_dpp(0, __float_as_int(x), 0x143, 0xF, 0xF, true); x = fmaxf(x, __int_as_float(t));
  return __int_as_float(__builtin_amdgcn_readlane(__float_as_int(x), 63));
}

// Full 64-lane sum via DPP (VALU pipe only); result valid in lane 63 only.
__device__ __forceinline__ int wave_sum64_lane63(int x){
  x += __builtin_amdgcn_update_dpp(0, x, 0x111, 0xF, 0xF, true);
  x += __builtin_amdgcn_update_dpp(0, x, 0x112, 0xF, 0xF, true);
  x += __builtin_amdgcn_update_dpp(0, x, 0x114, 0xF, 0xF, true);
  x += __builtin_amdgcn_update_dpp(0, x, 0x118, 0xF, 0xF, true);
  x += __builtin_amdgcn_update_dpp(0, x, 0x142, 0xF, 0xF, true);
  x += __builtin_amdgcn_update_dpp(0, x, 0x143, 0xF, 0xF, true);
  return x;
}

// One block per batch row: phase 1 (match + LSE, 9 passes of 1024 priors) writes
// rank values + meta ONLY to LDS; phase 2 (overrides + positive losses + top-k)
// follows after plain __syncthreads. No device-scope fences except the final
// 128-block ticket reduce (one fence per block, tid 0 only -- R0/R1-proven).
extern "C" __global__ void __launch_bounds__(BTS)
mb_row(const float* __restrict__ loc_data,
       const float* __restrict__ conf_data,
       const float* __restrict__ priors,
       const float* __restrict__ targets,
       float* __restrict__ rowres, int* __restrict__ ticket,
       float* __restrict__ out, int Bn)
{
  const int b = blockIdx.x, tid = threadIdx.x, lane = tid & 63, wid = tid >> 6;

  __shared__ __align__(16) float s_buf[NWS][64*NC];      // 86016 B conf staging
  __shared__ __align__(16) float s_val[PP];              // 34928 B rank values
  __shared__ __align__(16) unsigned int s_meta4[PP/4];   // 8732 B
  __shared__ unsigned long long s_keys[NWS][NB];         // 2560 B
  __shared__ float4 s_tr4[NB];
  __shared__ float s_lab[NB];
  __shared__ int   s_bp[NB];
  __shared__ int   s_tot[32];
  __shared__ float s_fa[NWS], s_fb[NWS], s_fc[NWS];
  __shared__ int   s_ia[NWS];
  __shared__ float s_rowll, s_rowpc;
  __shared__ int   s_npos, s_last;
  unsigned char* s_meta = (unsigned char*)s_meta4;
  float4* sv4 = reinterpret_cast<float4*>(s_val);

  // targets -> LDS for phase 2 (consumed only after later barriers)
  if (tid < NB*5){
    int n = tid/5, k2 = tid-n*5;
    float vvv = targets[((long)b*NB+n)*5+k2];
    if (k2<4) ((float*)&s_tr4[n])[k2]=vvv; else s_lab[n]=vvv;
  }
  if (tid < 32) s_tot[tid] = 0;

  // truths in lanes 0..19 registers (per wave), broadcast per-n via readlane
  float tx=0.f, ty=0.f, tz=0.f, tw=0.f;
  if (lane < NB){
    const float* tp = targets + ((long)b*NB + lane)*5;
    tx = tp[0]; ty = tp[1]; tz = tp[2]; tw = tp[3];
  }
  const float area_a = (tz-tx)*(tw-ty);                  // valid in lanes 0..19

  unsigned long long mykey = 0ULL;   // lane n: truth n's running winner key

  // ---------------- phase 1: match + LSE, 9 passes ----------------
  for (int pass=0; pass<NPASS; ++pass){
    const int q0 = pass*BTS + wid*64;
    const int cnt = (q0 < PP) ? ((PP - q0 < 64) ? (PP - q0) : 64) : 0;

    if (cnt == 64){
      // prior pass's ds_reads retired before overwriting the staging buffer
      asm volatile("s_waitcnt lgkmcnt(0)" ::: "memory");
      const char* g = (const char*)(conf_data + ((long)b*PP + q0)*NC) + lane*16;
      char* l0 = (char*)&s_buf[wid][0];
      #pragma unroll
      for (int i=0;i<5;i++)
        __builtin_amdgcn_global_load_lds(
          (const __attribute__((address_space(1))) void*)(g + i*1024),
          (__attribute__((address_space(3))) void*)(l0 + i*1024), 16, 0, 0);
      if (lane < 16)                                  // 5376 B = 5*1024 + 16*16
        __builtin_amdgcn_global_load_lds(
          (const __attribute__((address_space(1))) void*)(g + 5*1024),
          (__attribute__((address_space(3))) void*)(l0 + 5*1024), 16, 0, 0);
    } else if (cnt > 0){
      asm volatile("s_waitcnt lgkmcnt(0)" ::: "memory");
      const float4* cb4 = reinterpret_cast<const float4*>(conf_data + ((long)b*PP + q0)*NC);
      float4* sb4 = reinterpret_cast<float4*>(s_buf[wid]);
      const int tot4 = (cnt*NC) >> 2;
      for (int i=lane; i<tot4; i+=64) sb4[i] = cb4[i];
    }

    if (cnt > 0){
      const bool valid = (lane < cnt);
      const int p  = q0 + lane;
      const int pl = valid ? p : q0;
      float4 pr = reinterpret_cast<const float4*>(priors)[pl];

      float bx1 = pr.x - pr.z*0.5f, by1 = pr.y - pr.w*0.5f;
      float bx2 = pr.x + pr.z*0.5f, by2 = pr.y + pr.w*0.5f;
      float area_b = (bx2-bx1)*(by2-by1);
      float bestov = -1.0f; int bestn = 0;

      #pragma unroll 4
      for (int n=0;n<NB;n++){
        float t_x = __int_as_float(__builtin_amdgcn_readlane(__float_as_int(tx), n));
        float t_y = __int_as_float(__builtin_amdgcn_readlane(__float_as_int(ty), n));
        float t_z = __int_as_float(__builtin_amdgcn_readlane(__float_as_int(tz), n));
        float t_w = __int_as_float(__builtin_amdgcn_readlane(__float_as_int(tw), n));
        float aa  = __int_as_float(__builtin_amdgcn_readlane(__float_as_int(area_a), n));
        float lx=fmaxf(t_x,bx1), ly=fmaxf(t_y,by1);
        float rx=fminf(t_z,bx2), ry=fminf(t_w,by2);
        float iw=fmaxf(rx-lx,0.f), ih=fmaxf(ry-ly,0.f);
        float inter = iw*ih;
        float iou = inter * __builtin_amdgcn_rcpf(aa + area_b - inter);
        if (iou > bestov){ bestov=iou; bestn=n; }        // strict > = first-max over n

        // per-truth wave argmax: DPP max + ballot; tie -> lowest lane = min p.
        // wmax bits == winner's iou bits (all +normal/+0); key built on SALU.
        float iouv = valid ? iou : -1.0f;
        float wmax = wave_max64(iouv);
        unsigned long long mk = __ballot(valid && (iou == wmax));  // nonzero: lane0 valid
        int wlane = __ffsll((long long)mk) - 1;
        unsigned long long key = ((unsigned long long)__float_as_uint(wmax)<<32)
                               | (unsigned long long)(0xFFFFFFFFu - (unsigned)(q0 + wlane));
        if (lane == n && key > mykey) mykey = key;       // running max == cross-chunk max
      }

      asm volatile("s_waitcnt vmcnt(0)" ::: "memory");   // staging landed

      // logsumexp from LDS (stride-21: 2-way bank alias = free)
      const float* v = s_buf[wid] + lane*NC;
      float vv[NC];
      #pragma unroll
      for (int c=0;c<NC;c++) vv[c] = v[c];
      float m = vv[0];
      #pragma unroll
      for (int c=1;c<NC;c++) m = fmaxf(m, vv[c]);
      float s = 0.f;
      #pragma unroll
      for (int c=0;c<NC;c++) s += __expf(vv[c]-m);
      float lse = __logf(s) + m;
      if (valid){
        s_val[p]  = lse - vv[0];
        s_meta[p] = (unsigned char)((bestn<<1) | (bestov >= 0.5f ? 1 : 0));
      }
    }
  }
  if (lane < NB) s_keys[wid][lane] = mykey;
  __syncthreads();

  // ---------------- phase 2: selection for row b ----------------
  if (tid < NB){
    unsigned long long mx = s_keys[0][tid];
    #pragma unroll
    for (int w=1;w<NWS;w++) if (s_keys[w][tid] > mx) mx = s_keys[w][tid];
    s_bp[tid] = (int)(0xFFFFFFFFu - (unsigned)(mx & 0xFFFFFFFFULL));
  }
  __syncthreads();

  // overrides, ascending n (max n wins on collisions), forced positive
  if (tid==0){
    for (int n=0;n<NB;n++) s_meta[s_bp[n]] = (unsigned char)((n<<1)|1);
  }
  __syncthreads();

  // register-cache rank values; mask positives to 0 (post-override meta)
  float4 rv0 = sv4[tid];
  float4 rv1 = sv4[tid+1024];
  float4 rv2 = (tid < PP/4-2048) ? sv4[tid+2048] : make_float4(0.f,0.f,0.f,0.f);
  unsigned mm0 = s_meta4[tid];
  unsigned mm1 = s_meta4[tid+1024];
  unsigned mm2 = (tid < PP/4-2048) ? s_meta4[tid+2048] : 0u;
  if (mm0 & 0x00000001u) rv0.x = 0.f;
  if (mm0 & 0x00000100u) rv0.y = 0.f;
  if (mm0 & 0x00010000u) rv0.z = 0.f;
  if (mm0 & 0x01000000u) rv0.w = 0.f;
  if (mm1 & 0x00000001u) rv1.x = 0.f;
  if (mm1 & 0x00000100u) rv1.y = 0.f;
  if (mm1 & 0x00010000u) rv1.z = 0.f;
  if (mm1 & 0x01000000u) rv1.w = 0.f;
  if (mm2 & 0x00000001u) rv2.x = 0.f;
  if (mm2 & 0x00000100u) rv2.y = 0.f;
  if (mm2 & 0x00010000u) rv2.z = 0.f;
  if (mm2 & 0x01000000u) rv2.w = 0.f;

  // special case p==0 (clamped.at[0]): tid0-local registers
  int spec = 0; float delta = 0.f, val0 = 0.f;
  if (b==0 && tid==0 && !(mm0 & 1u)){
    float v0 = conf_data[0], v1 = conf_data[1];
    float r0 = rv0.x;                        // lse - v0 = true ce
    float r0p = r0 + v0 - v1;                // lse - v1 = ranking value
    delta = r0 - r0p;
    spec = 1;
    rv0.x = r0p; val0 = r0p;
  }

  // positive pass (identical iteration order; conf refetch is L2-hot)
  float ll=0.f, pc=0.f; int np=0;
  for (int p=tid;p<PP;p+=BTS){
    int mt = s_meta[p];
    if (mt & 1){
      np++;
      int n = mt>>1;
      int ct = (int)s_lab[n] + 1;
      const float* cp = conf_data + ((long)b*PP+p)*NC;
      float v0 = cp[0], vct = cp[ct];
      pc += s_val[p] + v0 - vct;             // lse - v[ct]
      float4 t = s_tr4[n];
      float4 prr = reinterpret_cast<const float4*>(priors)[p];
      float4 ld = reinterpret_cast<const float4*>(loc_data)[(long)b*PP+p];
      float g0 = ((t.x+t.z)*0.5f - prr.x)/(0.1f*prr.z);
      float g1 = ((t.y+t.w)*0.5f - prr.y)/(0.1f*prr.w);
      float g2 = __logf((t.z-t.x)/prr.z)/0.2f;
      float g3 = __logf((t.w-t.y)/prr.w)/0.2f;
      ll += sl1(ld.x-g0)+sl1(ld.y-g1)+sl1(ld.z-g2)+sl1(ld.w-g3);
    }
  }
  #pragma unroll
  for (int o=32;o;o>>=1){
    ll += __shfl_down(ll,o,64);
    pc += __shfl_down(pc,o,64);
    np += __shfl_down(np,o,64);
  }
  if (lane==0){ s_fa[wid]=ll; s_fb[wid]=pc; s_ia[wid]=np; }
  __syncthreads();
  if (tid==0){
    float a=0.f,c2=0.f; int ni=0;
    for (int w=0;w<NWS;w++){ a+=s_fa[w]; c2+=s_fb[w]; ni+=s_ia[w]; }
    s_rowll=a; s_rowpc=c2; s_npos=ni;
  }
  __syncthreads();
  const int num_pos = s_npos;
  int k = num_pos*3; if (k > PP-1) k = PP-1;

  float negsum = 0.f;
  if (k > 0){
    // k-th largest via binary search on float bits; DPP add + one LDS atomic per
    // wave + one broadcast read per iteration.
    unsigned lo=0u, hi=0x7f800000u;
    int it=0;
    while (lo < hi){
      unsigned mid = lo + ((hi - lo + 1u) >> 1);
      int c = (__float_as_uint(rv0.x)>=mid) + (__float_as_uint(rv0.y)>=mid)
            + (__float_as_uint(rv0.z)>=mid) + (__float_as_uint(rv0.w)>=mid)
            + (__float_as_uint(rv1.x)>=mid) + (__float_as_uint(rv1.y)>=mid)
            + (__float_as_uint(rv1.z)>=mid) + (__float_as_uint(rv1.w)>=mid)
            + (__float_as_uint(rv2.x)>=mid) + (__float_as_uint(rv2.y)>=mid)
            + (__float_as_uint(rv2.z)>=mid) + (__float_as_uint(rv2.w)>=mid);
      c = wave_sum64_lane63(c);
      if (lane==63) atomicAdd(&s_tot[it], c);
      __syncthreads();
      int tot = s_tot[it];
      if (tot >= k) lo = mid; else hi = mid - 1u;
      it++;                                   // <=31 iterations, s_tot[32] slots
    }
    const unsigned vstar = lo;

    int cg=0; float sg=0.f;
    #define ACC(x) if (__float_as_uint(x)>vstar){cg++;sg+=(x);}
    ACC(rv0.x) ACC(rv0.y) ACC(rv0.z) ACC(rv0.w)
    ACC(rv1.x) ACC(rv1.y) ACC(rv1.z) ACC(rv1.w)
    ACC(rv2.x) ACC(rv2.y) ACC(rv2.z) ACC(rv2.w)
    #undef ACC
    #pragma unroll
    for (int o=32;o;o>>=1){ cg += __shfl_down(cg,o,64); sg += __shfl_down(sg,o,64); }
    __syncthreads();
    if (lane==0){ s_ia[wid]=cg; s_fa[wid]=sg; }
    __syncthreads();
    if (tid==0){
      int cG=0; float sumG=0.f;
      for (int w=0;w<NWS;w++){ cG+=s_ia[w]; sumG+=s_fa[w]; }
      int tie = k - cG;                      // >=1; stable ties take lowest indices
      negsum = sumG + (float)tie * __uint_as_float(vstar);
      if (b==0 && spec && __float_as_uint(val0) >= vstar) negsum += delta;
    }
  }

  if (tid==0){
    rowres[b*4+0] = s_rowll;
    rowres[b*4+1] = s_rowpc + negsum;
    rowres[b*4+2] = (float)num_pos;
    __threadfence();
    int t = atomicAdd(ticket, 1);
    s_last = (t == Bn - 1) ? 1 : 0;
  }
  __syncthreads();

  if (s_last){
    __threadfence();
    float a0=0.f, a1=0.f, a2=0.f;
    for (int i=tid;i<Bn;i+=BTS){
      a0 += rowres[i*4+0]; a1 += rowres[i*4+1]; a2 += rowres[i*4+2];
    }
    #pragma unroll
    for (int o=32;o;o>>=1){
      a0 += __shfl_down(a0,o,64);
      a1 += __shfl_down(a1,o,64);
      a2 += __shfl_down(a2,o,64);
    }
    if (lane==0){ s_fa[wid]=a0; s_fb[wid]=a1; s_fc[wid]=a2; }
    __syncthreads();
    if (tid==0){
      float A0=0.f,A1=0.f,A2=0.f;
      for (int w=0;w<NWS;w++){ A0+=s_fa[w]; A1+=s_fb[w]; A2+=s_fc[w]; }
      out[0] = A0/A2;
      out[1] = A1/A2;
    }
  }
}

extern "C" void kernel_launch(void* const* d_in, const int* in_sizes, int n_in,
                              void* d_out, int out_size, void* d_ws, size_t ws_size,
                              hipStream_t stream) {
  const float* loc     = (const float*)d_in[0];
  const float* conf    = (const float*)d_in[1];
  const float* priors  = (const float*)d_in[2];
  const float* targets = (const float*)d_in[3];
  float* out = (float*)d_out;
  int B = in_sizes[0] / (PP*4);

  char* ws = (char*)d_ws;
  int*   ticket = (int*)ws;                       // [0,4)
  float* rowres = (float*)(ws + 4096);

  hipMemsetAsync(d_ws, 0, 64, stream);            // ticket
  hipLaunchKernelGGL(mb_row, dim3(B), dim3(BTS), 0, stream,
                     loc, conf, priors, targets, rowres, ticket, out, B);
}

// Round 4
// 206.311 us; speedup vs baseline: 2.5127x; 1.1492x over previous
//
#include <hip/hip_runtime.h>

#define PP 8732
#define NB 20
#define NC 21
#define BTH 256
#define NCH 9           // ceil(PP/1024): chunks of 1024 priors (4 waves x 256)
#define BTS 1024
#define NWS (BTS/64)

__device__ __forceinline__ float sl1(float d){
  float a = fabsf(d);
  return a < 1.0f ? 0.5f*a*a : a - 0.5f;
}

// Full 64-lane max via DPP (VALU pipe only); result valid in lane 63, broadcast
// to all lanes through readlane. bound_ctrl=1 injects 0.0 at row edges -- harmless
// here since every participating value is >= 0 or the injected 0 ties a real 0.
__device__ __forceinline__ float wave_max64(float x){
  int t;
  t = __builtin_amdgcn_update_dpp(0, __float_as_int(x), 0x111, 0xF, 0xF, true); x = fmaxf(x, __int_as_float(t));
  t = __builtin_amdgcn_update_dpp(0, __float_as_int(x), 0x112, 0xF, 0xF, true); x = fmaxf(x, __int_as_float(t));
  t = __builtin_amdgcn_update_dpp(0, __float_as_int(x), 0x114, 0xF, 0xF, true); x = fmaxf(x, __int_as_float(t));
  t = __builtin_amdgcn_update_dpp(0, __float_as_int(x), 0x118, 0xF, 0xF, true); x = fmaxf(x, __int_as_float(t));
  t = __builtin_amdgcn_update_dpp(0, __float_as_int(x), 0x142, 0xF, 0xF, true); x = fmaxf(x, __int_as_float(t));
  t = __builtin_amdgcn_update_dpp(0, __float_as_int(x), 0x143, 0xF, 0xF, true); x = fmaxf(x, __int_as_float(t));
  return __int_as_float(__builtin_amdgcn_readlane(__float_as_int(x), 63));
}

// Full 64-lane sum via DPP (VALU pipe only); result valid in lane 63 only.
__device__ __forceinline__ int wave_sum64_lane63(int x){
  x += __builtin_amdgcn_update_dpp(0, x, 0x111, 0xF, 0xF, true);
  x += __builtin_amdgcn_update_dpp(0, x, 0x112, 0xF, 0xF, true);
  x += __builtin_amdgcn_update_dpp(0, x, 0x114, 0xF, 0xF, true);
  x += __builtin_amdgcn_update_dpp(0, x, 0x118, 0xF, 0xF, true);
  x += __builtin_amdgcn_update_dpp(0, x, 0x142, 0xF, 0xF, true);
  x += __builtin_amdgcn_update_dpp(0, x, 0x143, 0xF, 0xF, true);
  return x;
}

// ---- 1: fused match + logsumexp. grid (B, NCH), 256 threads ----
// Each lane owns 4 CONSECUTIVE priors (wave = 256 priors): the per-truth DPP
// reduce amortizes over 4x more priors (0.36 vs 0.55 instr/prior/truth).
// Consecutive-p-per-lane keeps argmax tie-break exact: lane-local ascending-i
// strict '>' picks min-p; lane j's priors all < lane j+1's, so ballot+ffs is
// still global-min-p. Truths broadcast from LDS (off the VALU pipe). Conf goes
// direct to registers for LSE (no staging, no vmcnt choreography).
extern "C" __global__ void __launch_bounds__(BTH)
mb_main(const float* __restrict__ conf_data,
        const float* __restrict__ priors,
        const float* __restrict__ targets,
        float* __restrict__ rankneg,
        unsigned char* __restrict__ meta,
        unsigned long long* __restrict__ keys2)
{
  const int b = blockIdx.x, chunk = blockIdx.y;
  const int tid = threadIdx.x, lane = tid & 63, wid = tid >> 6;
  const int q0w = chunk*1024 + wid*256;          // wave's base prior
  const int p0  = q0w + 4*lane;                  // lane's first prior

  __shared__ float4 s_tr4[NB];
  __shared__ float  s_area[NB];
  __shared__ unsigned long long s_keys[4][NB];

  if (tid < NB){
    const float* tp = targets + ((long)b*NB + tid)*5;
    float a0=tp[0], a1=tp[1], a2=tp[2], a3=tp[3];
    s_tr4[tid]  = make_float4(a0,a1,a2,a3);
    s_area[tid] = (a2-a0)*(a3-a1);
  }
  __syncthreads();   // before any other memory traffic exists -> cheap

  unsigned long long mykey = 0ULL;   // lane n: truth n's winner key for this wave

  if (q0w < PP){
    const bool fullwave = (q0w + 256 <= PP);

    // per-prior constants; out-of-range priors become degenerate far boxes:
    // inter=0, area_b=0 -> iou = 0*rcp(aa) = 0, and their p only wins a tie
    // against ALL-zero rows via lanes ABOVE every valid lane (valid lanes are
    // lower-numbered), so ffs never picks them over a valid candidate.
    float bx1[4], by1[4], bx2[4], by2[4], areab[4];
    #pragma unroll
    for (int i=0;i<4;i++){
      int p = p0 + i;
      int pc = (p < PP) ? p : 0;
      float4 pr = reinterpret_cast<const float4*>(priors)[pc];
      float x1 = pr.x - pr.z*0.5f, y1 = pr.y - pr.w*0.5f;
      float x2 = pr.x + pr.z*0.5f, y2 = pr.y + pr.w*0.5f;
      if (!fullwave && p >= PP){ x1=3e9f; y1=3e9f; x2=3e9f; y2=3e9f; }
      bx1[i]=x1; by1[i]=y1; bx2[i]=x2; by2[i]=y2;
      areab[i] = (x2-x1)*(y2-y1);
    }

    float bestov[4] = {-1.f,-1.f,-1.f,-1.f};
    int   bestn [4] = {0,0,0,0};

    #pragma unroll 4
    for (int n=0;n<NB;n++){
      float4 t = s_tr4[n];                       // ds_read_b128 broadcast
      float aa = s_area[n];                      // ds_read_b32 broadcast
      float candiou = -1.0f; unsigned candp = 0u;
      #pragma unroll
      for (int i=0;i<4;i++){
        float lx=fmaxf(t.x,bx1[i]), ly=fmaxf(t.y,by1[i]);
        float rx=fminf(t.z,bx2[i]), ry=fminf(t.w,by2[i]);
        float iw=fmaxf(rx-lx,0.f), ih=fmaxf(ry-ly,0.f);
        float inter = iw*ih;
        float iou = inter * __builtin_amdgcn_rcpf(aa + areab[i] - inter);
        if (iou > bestov[i]){ bestov[i]=iou; bestn[i]=n; }     // first-max over n
        if (iou > candiou){ candiou=iou; candp=(unsigned)(p0+i); } // min-p tie (asc i, strict >)
      }
      // wave argmax for truth n: DPP max + ballot; lowest matching lane = min p
      float wmax = wave_max64(candiou);
      unsigned long long mk = __ballot(candiou == wmax);   // nonzero: some lane matches
      int wlane = __ffsll((long long)mk) - 1;
      unsigned wp = (unsigned)__builtin_amdgcn_readlane((int)candp, wlane);
      unsigned long long key = ((unsigned long long)__float_as_uint(wmax)<<32)
                             | (unsigned long long)(0xFFFFFFFFu - wp);
      if (lane == n) mykey = key;
    }

    // LSE per owned prior, conf direct to registers (identical value order)
    float rr4[4] = {0.f,0.f,0.f,0.f};
    unsigned metab = 0u;
    #pragma unroll
    for (int i=0;i<4;i++){
      int p = p0 + i;
      if (p < PP){
        const float* cb = conf_data + ((long)b*PP + p)*NC;
        const float4* cb4 = reinterpret_cast<const float4*>(cb);  // dwordx4, 4B-aligned ok
        float4 ca0=cb4[0], ca1=cb4[1], ca2=cb4[2], ca3=cb4[3], ca4=cb4[4];
        float c20 = cb[20];
        float vv[NC] = {ca0.x,ca0.y,ca0.z,ca0.w, ca1.x,ca1.y,ca1.z,ca1.w,
                        ca2.x,ca2.y,ca2.z,ca2.w, ca3.x,ca3.y,ca3.z,ca3.w,
                        ca4.x,ca4.y,ca4.z,ca4.w, c20};
        float m = vv[0];
        #pragma unroll
        for (int c=1;c<NC;c++) m = fmaxf(m, vv[c]);
        float s = 0.f;
        #pragma unroll
        for (int c=0;c<NC;c++) s += __expf(vv[c]-m);
        float lse = __logf(s) + m;
        rr4[i] = lse - vv[0];
        metab |= ((unsigned)((bestn[i]<<1) | (bestov[i] >= 0.5f ? 1 : 0))) << (8*i);
      }
    }

    if (p0 + 3 < PP){
      *reinterpret_cast<float4*>(rankneg + (long)b*PP + p0) =
          make_float4(rr4[0],rr4[1],rr4[2],rr4[3]);
      *reinterpret_cast<unsigned*>(meta + (long)b*PP + p0) = metab;   // 4-aligned (p0%4==0)
    } else {
      #pragma unroll
      for (int i=0;i<4;i++){
        int p = p0 + i;
        if (p < PP){
          rankneg[(long)b*PP + p] = rr4[i];
          meta[(long)b*PP + p] = (unsigned char)((metab >> (8*i)) & 0xFF);
        }
      }
    }
  }

  if (lane < NB) s_keys[wid][lane] = mykey;       // out-of-range waves write zeros
  __syncthreads();
  if (tid < NB){
    unsigned long long mx = s_keys[0][tid];
    #pragma unroll
    for (int w=1;w<4;w++) if (s_keys[w][tid] > mx) mx = s_keys[w][tid];
    keys2[((long)b*NCH + chunk)*NB + tid] = mx;
  }
}

// ---- 2: fused scatter + positive losses + top-k + final reduce. grid (B) ----
extern "C" __global__ void __launch_bounds__(BTS)
mb_select(const float* __restrict__ loc_data,
          const float* __restrict__ conf_data,
          const float* __restrict__ priors,
          const float* __restrict__ targets,
          const float* __restrict__ rankneg,
          const unsigned char* __restrict__ meta,
          const unsigned long long* __restrict__ keys2,
          float* __restrict__ rowres, int* __restrict__ ticket,
          float* __restrict__ out, int Bn)
{
  const int b = blockIdx.x, tid = threadIdx.x, lane = tid & 63, wid = tid >> 6;
  __shared__ __align__(16) float s_val[PP];              // 34928
  __shared__ __align__(16) unsigned int s_meta4[PP/4];   // 8732
  __shared__ float4 s_tr4[NB];
  __shared__ float s_lab[NB];
  __shared__ int   s_bp[NB];
  __shared__ int   s_tot[32];                            // per-iteration count slots
  __shared__ float s_fa[NWS], s_fb[NWS], s_fc[NWS];
  __shared__ int   s_ia[NWS];
  __shared__ float s_rowll, s_rowpc;
  __shared__ int   s_npos, s_last;
  unsigned char* s_meta = (unsigned char*)s_meta4;
  float4* sv4 = reinterpret_cast<float4*>(s_val);

  const float4* rr = reinterpret_cast<const float4*>(rankneg + (long)b*PP);
  for (int i=tid;i<PP/4;i+=BTS) sv4[i]=rr[i];
  const unsigned int* mr = reinterpret_cast<const unsigned int*>(meta + (long)b*PP);
  for (int i=tid;i<PP/4;i+=BTS) s_meta4[i]=mr[i];
  if (tid < NB*5){
    int n = tid/5, k2 = tid-n*5;
    float vv = targets[((long)b*NB+n)*5+k2];
    if (k2<4) ((float*)&s_tr4[n])[k2]=vv; else s_lab[n]=vv;
  }
  if (tid < NB){
    unsigned long long mx = 0ULL;
    #pragma unroll
    for (int c=0;c<NCH;c++){
      unsigned long long kk = keys2[((long)b*NCH + c)*NB + tid];
      if (kk > mx) mx = kk;
    }
    s_bp[tid] = (int)(0xFFFFFFFFu - (unsigned)(mx & 0xFFFFFFFFULL));
  }
  if (tid < 32) s_tot[tid] = 0;
  __syncthreads();

  // overrides, ascending n (max n wins on collisions), forced positive
  if (tid==0){
    for (int n=0;n<NB;n++) s_meta[s_bp[n]] = (unsigned char)((n<<1)|1);
  }
  __syncthreads();

  // register-cache rank values; mask positives to 0 (post-override meta)
  float4 rv0 = sv4[tid];
  float4 rv1 = sv4[tid+1024];
  float4 rv2 = (tid < PP/4-2048) ? sv4[tid+2048] : make_float4(0.f,0.f,0.f,0.f);
  unsigned mm0 = s_meta4[tid];
  unsigned mm1 = s_meta4[tid+1024];
  unsigned mm2 = (tid < PP/4-2048) ? s_meta4[tid+2048] : 0u;
  if (mm0 & 0x00000001u) rv0.x = 0.f;
  if (mm0 & 0x00000100u) rv0.y = 0.f;
  if (mm0 & 0x00010000u) rv0.z = 0.f;
  if (mm0 & 0x01000000u) rv0.w = 0.f;
  if (mm1 & 0x00000001u) rv1.x = 0.f;
  if (mm1 & 0x00000100u) rv1.y = 0.f;
  if (mm1 & 0x00010000u) rv1.z = 0.f;
  if (mm1 & 0x01000000u) rv1.w = 0.f;
  if (mm2 & 0x00000001u) rv2.x = 0.f;
  if (mm2 & 0x00000100u) rv2.y = 0.f;
  if (mm2 & 0x00010000u) rv2.z = 0.f;
  if (mm2 & 0x01000000u) rv2.w = 0.f;

  // special case p==0 (clamped.at[0]): tid0-local registers
  int spec = 0; float delta = 0.f, val0 = 0.f;
  if (b==0 && tid==0 && !(mm0 & 1u)){
    float v0 = conf_data[0], v1 = conf_data[1];
    float r0 = rv0.x;                        // lse - v0 = true ce
    float r0p = r0 + v0 - v1;                // lse - v1 = ranking value
    delta = r0 - r0p;
    spec = 1;
    rv0.x = r0p; val0 = r0p;
  }

  // positive pass (identical iteration order; conf refetch is L2-hot)
  float ll=0.f, pc=0.f; int np=0;
  for (int p=tid;p<PP;p+=BTS){
    int mt = s_meta[p];
    if (mt & 1){
      np++;
      int n = mt>>1;
      int ct = (int)s_lab[n] + 1;
      const float* cp = conf_data + ((long)b*PP+p)*NC;
      float v0 = cp[0], vct = cp[ct];
      pc += s_val[p] + v0 - vct;             // lse - v[ct]
      float4 t = s_tr4[n];
      float4 prr = reinterpret_cast<const float4*>(priors)[p];
      float4 ld = reinterpret_cast<const float4*>(loc_data)[(long)b*PP+p];
      float g0 = ((t.x+t.z)*0.5f - prr.x)/(0.1f*prr.z);
      float g1 = ((t.y+t.w)*0.5f - prr.y)/(0.1f*prr.w);
      float g2 = __logf((t.z-t.x)/prr.z)/0.2f;
      float g3 = __logf((t.w-t.y)/prr.w)/0.2f;
      ll += sl1(ld.x-g0)+sl1(ld.y-g1)+sl1(ld.z-g2)+sl1(ld.w-g3);
    }
  }
  #pragma unroll
  for (int o=32;o;o>>=1){
    ll += __shfl_down(ll,o,64);
    pc += __shfl_down(pc,o,64);
    np += __shfl_down(np,o,64);
  }
  if (lane==0){ s_fa[wid]=ll; s_fb[wid]=pc; s_ia[wid]=np; }
  __syncthreads();
  if (tid==0){
    float a=0.f,c2=0.f; int ni=0;
    for (int w=0;w<NWS;w++){ a+=s_fa[w]; c2+=s_fb[w]; ni+=s_ia[w]; }
    s_rowll=a; s_rowpc=c2; s_npos=ni;
  }
  __syncthreads();
  const int num_pos = s_npos;
  int k = num_pos*3; if (k > PP-1) k = PP-1;

  float negsum = 0.f;
  if (k > 0){
    // k-th largest via binary search on float bits; DPP add + one LDS atomic per
    // wave + one broadcast read per iteration.
    unsigned lo=0u, hi=0x7f800000u;
    int it=0;
    while (lo < hi){
      unsigned mid = lo + ((hi - lo + 1u) >> 1);
      int c = (__float_as_uint(rv0.x)>=mid) + (__float_as_uint(rv0.y)>=mid)
            + (__float_as_uint(rv0.z)>=mid) + (__float_as_uint(rv0.w)>=mid)
            + (__float_as_uint(rv1.x)>=mid) + (__float_as_uint(rv1.y)>=mid)
            + (__float_as_uint(rv1.z)>=mid) + (__float_as_uint(rv1.w)>=mid)
            + (__float_as_uint(rv2.x)>=mid) + (__float_as_uint(rv2.y)>=mid)
            + (__float_as_uint(rv2.z)>=mid) + (__float_as_uint(rv2.w)>=mid);
      c = wave_sum64_lane63(c);
      if (lane==63) atomicAdd(&s_tot[it], c);
      __syncthreads();
      int tot = s_tot[it];
      if (tot >= k) lo = mid; else hi = mid - 1u;
      it++;                                   // <=31 iterations, s_tot[32] slots
    }
    const unsigned vstar = lo;

    int cg=0; float sg=0.f;
    #define ACC(x) if (__float_as_uint(x)>vstar){cg++;sg+=(x);}
    ACC(rv0.x) ACC(rv0.y) ACC(rv0.z) ACC(rv0.w)
    ACC(rv1.x) ACC(rv1.y) ACC(rv1.z) ACC(rv1.w)
    ACC(rv2.x) ACC(rv2.y) ACC(rv2.z) ACC(rv2.w)
    #undef ACC
    #pragma unroll
    for (int o=32;o;o>>=1){ cg += __shfl_down(cg,o,64); sg += __shfl_down(sg,o,64); }
    __syncthreads();
    if (lane==0){ s_ia[wid]=cg; s_fa[wid]=sg; }
    __syncthreads();
    if (tid==0){
      int cG=0; float sumG=0.f;
      for (int w=0;w<NWS;w++){ cG+=s_ia[w]; sumG+=s_fa[w]; }
      int tie = k - cG;                      // >=1; stable ties take lowest indices
      negsum = sumG + (float)tie * __uint_as_float(vstar);
      if (b==0 && spec && __float_as_uint(val0) >= vstar) negsum += delta;
    }
  }

  if (tid==0){
    rowres[b*4+0] = s_rowll;
    rowres[b*4+1] = s_rowpc + negsum;
    rowres[b*4+2] = (float)num_pos;
    __threadfence();
    int t = atomicAdd(ticket, 1);
    s_last = (t == Bn - 1) ? 1 : 0;
  }
  __syncthreads();

  if (s_last){
    __threadfence();
    float a0=0.f, a1=0.f, a2=0.f;
    for (int i=tid;i<Bn;i+=BTS){
      a0 += rowres[i*4+0]; a1 += rowres[i*4+1]; a2 += rowres[i*4+2];
    }
    #pragma unroll
    for (int o=32;o;o>>=1){
      a0 += __shfl_down(a0,o,64);
      a1 += __shfl_down(a1,o,64);
      a2 += __shfl_down(a2,o,64);
    }
    if (lane==0){ s_fa[wid]=a0; s_fb[wid]=a1; s_fc[wid]=a2; }
    __syncthreads();
    if (tid==0){
      float A0=0.f,A1=0.f,A2=0.f;
      for (int w=0;w<NWS;w++){ A0+=s_fa[w]; A1+=s_fb[w]; A2+=s_fc[w]; }
      out[0] = A0/A2;
      out[1] = A1/A2;
    }
  }
}

extern "C" void kernel_launch(void* const* d_in, const int* in_sizes, int n_in,
                              void* d_out, int out_size, void* d_ws, size_t ws_size,
                              hipStream_t stream) {
  const float* loc     = (const float*)d_in[0];
  const float* conf    = (const float*)d_in[1];
  const float* priors  = (const float*)d_in[2];
  const float* targets = (const float*)d_in[3];
  float* out = (float*)d_out;
  int B = in_sizes[0] / (PP*4);

  char* ws = (char*)d_ws;
  int*   ticket = (int*)ws;
  float* rowres = (float*)(ws + 64);
  unsigned long long* keys2 = (unsigned long long*)(ws + 4096);
  size_t off_rank = 4096 + (size_t)B*NCH*NB*8;
  float* rankneg = (float*)(ws + off_rank);
  unsigned char* metaa = (unsigned char*)(ws + off_rank + (size_t)B*PP*4);

  hipMemsetAsync(d_ws, 0, 64, stream);
  hipLaunchKernelGGL(mb_main,   dim3(B, NCH), dim3(BTH), 0, stream,
                     conf, priors, targets, rankneg, metaa, keys2);
  hipLaunchKernelGGL(mb_select, dim3(B), dim3(BTS), 0, stream,
                     loc, conf, priors, targets, rankneg, metaa, keys2,
                     rowres, ticket, out, B);
}

// Round 5
// 199.427 us; speedup vs baseline: 2.5994x; 1.0345x over previous
//
#include <hip/hip_runtime.h>

#define PP 8732
#define NB 20
#define NC 21
#define BTH 256
#define CHP 512         // priors per block (2 per lane, 128 per wave)
#define NCH 18          // ceil(PP/CHP): 17*512=8704, tail chunk has 28
#define BTS 1024
#define NWS (BTS/64)

__device__ __forceinline__ float sl1(float d){
  float a = fabsf(d);
  return a < 1.0f ? 0.5f*a*a : a - 0.5f;
}

// Full 64-lane max via DPP (VALU pipe only); result valid in lane 63, broadcast
// to all lanes through readlane. bound_ctrl=1 injects 0.0 at row edges -- harmless
// here since every participating value is >= 0 (candiou is an IoU >= 0).
__device__ __forceinline__ float wave_max64(float x){
  int t;
  t = __builtin_amdgcn_update_dpp(0, __float_as_int(x), 0x111, 0xF, 0xF, true); x = fmaxf(x, __int_as_float(t));
  t = __builtin_amdgcn_update_dpp(0, __float_as_int(x), 0x112, 0xF, 0xF, true); x = fmaxf(x, __int_as_float(t));
  t = __builtin_amdgcn_update_dpp(0, __float_as_int(x), 0x114, 0xF, 0xF, true); x = fmaxf(x, __int_as_float(t));
  t = __builtin_amdgcn_update_dpp(0, __float_as_int(x), 0x118, 0xF, 0xF, true); x = fmaxf(x, __int_as_float(t));
  t = __builtin_amdgcn_update_dpp(0, __float_as_int(x), 0x142, 0xF, 0xF, true); x = fmaxf(x, __int_as_float(t));
  t = __builtin_amdgcn_update_dpp(0, __float_as_int(x), 0x143, 0xF, 0xF, true); x = fmaxf(x, __int_as_float(t));
  return __int_as_float(__builtin_amdgcn_readlane(__float_as_int(x), 63));
}

// Full 64-lane sum via DPP (VALU pipe only); result valid in lane 63 only.
__device__ __forceinline__ int wave_sum64_lane63(int x){
  x += __builtin_amdgcn_update_dpp(0, x, 0x111, 0xF, 0xF, true);
  x += __builtin_amdgcn_update_dpp(0, x, 0x112, 0xF, 0xF, true);
  x += __builtin_amdgcn_update_dpp(0, x, 0x114, 0xF, 0xF, true);
  x += __builtin_amdgcn_update_dpp(0, x, 0x118, 0xF, 0xF, true);
  x += __builtin_amdgcn_update_dpp(0, x, 0x142, 0xF, 0xF, true);
  x += __builtin_amdgcn_update_dpp(0, x, 0x143, 0xF, 0xF, true);
  return x;
}

// ---- 1: fused match + logsumexp. grid (B, NCH), 256 threads ----
// 2 consecutive priors per lane: per-truth DPP reduce amortizes over 128 priors
// (0.42 instr/prior/truth) while grid stays 2304 blocks = 36 waves/CU (vs R4's
// 18). Truths live in lanes 0..19 REGISTERS, broadcast via readlane -- zero
// memory latency inside the 20-truth loop (R4's in-loop ds_read reverted).
// Conf direct to registers (168B lane stride spans 10.75KB/wave <= L1); loads
// can hoist above the ~1100-instr match loop under the 85-VGPR cap.
// Tie-breaks: lane-local ascending-i strict '>' picks min-p; lane j's priors
// all < lane j+1's, so ballot+ffs+readlane(candp) is global-min-p. OOR priors
// become degenerate far boxes: iou == +0, can only win all-zero ties through
// lanes above every valid lane, which ffs never picks.
extern "C" __global__ void __launch_bounds__(BTH, 6)
mb_main(const float* __restrict__ conf_data,
        const float* __restrict__ priors,
        const float* __restrict__ targets,
        float* __restrict__ rankneg,
        unsigned char* __restrict__ meta,
        unsigned long long* __restrict__ keys2)
{
  const int b = blockIdx.x, chunk = blockIdx.y;
  const int tid = threadIdx.x, lane = tid & 63, wid = tid >> 6;
  const int q0w = chunk*CHP + wid*128;           // wave's base prior
  const int p0  = q0w + 2*lane;                  // lane's first prior

  __shared__ unsigned long long s_keys[4][NB];

  // truths in lanes 0..19 registers (per wave), broadcast per-n via readlane
  float tx=0.f, ty=0.f, tz=0.f, tw=0.f;
  if (lane < NB){
    const float* tp = targets + ((long)b*NB + lane)*5;
    tx = tp[0]; ty = tp[1]; tz = tp[2]; tw = tp[3];
  }
  const float area_a = (tz-tx)*(tw-ty);          // valid in lanes 0..19

  unsigned long long mykey = 0ULL;   // lane n: truth n's winner key for this wave

  if (q0w < PP){
    float bx1[2], by1[2], bx2[2], by2[2], areab[2];
    #pragma unroll
    for (int i=0;i<2;i++){
      int p = p0 + i;
      int pc = (p < PP) ? p : 0;
      float4 pr = reinterpret_cast<const float4*>(priors)[pc];
      float x1 = pr.x - pr.z*0.5f, y1 = pr.y - pr.w*0.5f;
      float x2 = pr.x + pr.z*0.5f, y2 = pr.y + pr.w*0.5f;
      if (p >= PP){ x1=3e9f; y1=3e9f; x2=3e9f; y2=3e9f; }   // iou == +0 exactly
      bx1[i]=x1; by1[i]=y1; bx2[i]=x2; by2[i]=y2;
      areab[i] = (x2-x1)*(y2-y1);
    }

    float bestov[2] = {-1.f,-1.f};
    int   bestn [2] = {0,0};

    #pragma unroll
    for (int n=0;n<NB;n++){
      float t_x = __int_as_float(__builtin_amdgcn_readlane(__float_as_int(tx), n));
      float t_y = __int_as_float(__builtin_amdgcn_readlane(__float_as_int(ty), n));
      float t_z = __int_as_float(__builtin_amdgcn_readlane(__float_as_int(tz), n));
      float t_w = __int_as_float(__builtin_amdgcn_readlane(__float_as_int(tw), n));
      float aa  = __int_as_float(__builtin_amdgcn_readlane(__float_as_int(area_a), n));
      float candiou = -1.0f; unsigned candp = 0u;
      #pragma unroll
      for (int i=0;i<2;i++){
        float lx=fmaxf(t_x,bx1[i]), ly=fmaxf(t_y,by1[i]);
        float rx=fminf(t_z,bx2[i]), ry=fminf(t_w,by2[i]);
        float iw=fmaxf(rx-lx,0.f), ih=fmaxf(ry-ly,0.f);
        float inter = iw*ih;
        float iou = inter * __builtin_amdgcn_rcpf(aa + areab[i] - inter);
        if (iou > bestov[i]){ bestov[i]=iou; bestn[i]=n; }         // first-max over n
        if (iou > candiou){ candiou=iou; candp=(unsigned)(p0+i); } // min-p (asc i, strict >)
      }
      // wave argmax for truth n: DPP max + ballot; lowest matching lane = min p.
      // wmax bits == winner's iou bits (fmax over +0/+normals preserves bits).
      float wmax = wave_max64(candiou);
      unsigned long long mk = __ballot(candiou == wmax);   // lane 0 always has candiou>=0
      int wlane = __ffsll((long long)mk) - 1;
      unsigned wp = (unsigned)__builtin_amdgcn_readlane((int)candp, wlane);
      unsigned long long key = ((unsigned long long)__float_as_uint(wmax)<<32)
                             | (unsigned long long)(0xFFFFFFFFu - wp);
      if (lane == n) mykey = key;
    }

    // LSE per owned prior, conf direct to registers (identical value order)
    if (p0 < PP){                       // PP even, p0 even => p0+1 < PP too
      float rr2[2];
      unsigned metab = 0u;
      #pragma unroll
      for (int i=0;i<2;i++){
        const float* cb = conf_data + ((long)b*PP + p0 + i)*NC;
        const float4* cb4 = reinterpret_cast<const float4*>(cb);  // dwordx4, 4B-aligned ok
        float4 ca0=cb4[0], ca1=cb4[1], ca2=cb4[2], ca3=cb4[3], ca4=cb4[4];
        float c20 = cb[20];
        float vv[NC] = {ca0.x,ca0.y,ca0.z,ca0.w, ca1.x,ca1.y,ca1.z,ca1.w,
                        ca2.x,ca2.y,ca2.z,ca2.w, ca3.x,ca3.y,ca3.z,ca3.w,
                        ca4.x,ca4.y,ca4.z,ca4.w, c20};
        float m = vv[0];
        #pragma unroll
        for (int c=1;c<NC;c++) m = fmaxf(m, vv[c]);
        float s = 0.f;
        #pragma unroll
        for (int c=0;c<NC;c++) s += __expf(vv[c]-m);
        float lse = __logf(s) + m;
        rr2[i] = lse - vv[0];
        metab |= ((unsigned)((bestn[i]<<1) | (bestov[i] >= 0.5f ? 1 : 0))) << (8*i);
      }
      *reinterpret_cast<float2*>(rankneg + (long)b*PP + p0) = make_float2(rr2[0], rr2[1]);
      *reinterpret_cast<unsigned short*>(meta + (long)b*PP + p0) =
          (unsigned short)(metab & 0xFFFFu);
    }
  }

  if (lane < NB) s_keys[wid][lane] = mykey;       // out-of-range waves write zeros
  __syncthreads();
  if (tid < NB){
    unsigned long long mx = s_keys[0][tid];
    #pragma unroll
    for (int w=1;w<4;w++) if (s_keys[w][tid] > mx) mx = s_keys[w][tid];
    keys2[((long)b*NCH + chunk)*NB + tid] = mx;
  }
}

// ---- 2: fused scatter + positive losses + top-k + final reduce. grid (B) ----
extern "C" __global__ void __launch_bounds__(BTS)
mb_select(const float* __restrict__ loc_data,
          const float* __restrict__ conf_data,
          const float* __restrict__ priors,
          const float* __restrict__ targets,
          const float* __restrict__ rankneg,
          const unsigned char* __restrict__ meta,
          const unsigned long long* __restrict__ keys2,
          float* __restrict__ rowres, int* __restrict__ ticket,
          float* __restrict__ out, int Bn)
{
  const int b = blockIdx.x, tid = threadIdx.x, lane = tid & 63, wid = tid >> 6;
  __shared__ __align__(16) float s_val[PP];              // 34928
  __shared__ __align__(16) unsigned int s_meta4[PP/4];   // 8732
  __shared__ float4 s_tr4[NB];
  __shared__ float s_lab[NB];
  __shared__ int   s_bp[NB];
  __shared__ int   s_tot[32];                            // per-iteration count slots
  __shared__ float s_fa[NWS], s_fb[NWS], s_fc[NWS];
  __shared__ int   s_ia[NWS];
  __shared__ float s_rowll, s_rowpc;
  __shared__ int   s_npos, s_last;
  unsigned char* s_meta = (unsigned char*)s_meta4;
  float4* sv4 = reinterpret_cast<float4*>(s_val);

  const float4* rr = reinterpret_cast<const float4*>(rankneg + (long)b*PP);
  for (int i=tid;i<PP/4;i+=BTS) sv4[i]=rr[i];
  const unsigned int* mr = reinterpret_cast<const unsigned int*>(meta + (long)b*PP);
  for (int i=tid;i<PP/4;i+=BTS) s_meta4[i]=mr[i];
  if (tid < NB*5){
    int n = tid/5, k2 = tid-n*5;
    float vv = targets[((long)b*NB+n)*5+k2];
    if (k2<4) ((float*)&s_tr4[n])[k2]=vv; else s_lab[n]=vv;
  }
  if (tid < NB){
    unsigned long long mx = 0ULL;
    #pragma unroll
    for (int c=0;c<NCH;c++){
      unsigned long long kk = keys2[((long)b*NCH + c)*NB + tid];
      if (kk > mx) mx = kk;
    }
    s_bp[tid] = (int)(0xFFFFFFFFu - (unsigned)(mx & 0xFFFFFFFFULL));
  }
  if (tid < 32) s_tot[tid] = 0;
  __syncthreads();

  // overrides, ascending n (max n wins on collisions), forced positive
  if (tid==0){
    for (int n=0;n<NB;n++) s_meta[s_bp[n]] = (unsigned char)((n<<1)|1);
  }
  __syncthreads();

  // register-cache rank values; mask positives to 0 (post-override meta)
  float4 rv0 = sv4[tid];
  float4 rv1 = sv4[tid+1024];
  float4 rv2 = (tid < PP/4-2048) ? sv4[tid+2048] : make_float4(0.f,0.f,0.f,0.f);
  unsigned mm0 = s_meta4[tid];
  unsigned mm1 = s_meta4[tid+1024];
  unsigned mm2 = (tid < PP/4-2048) ? s_meta4[tid+2048] : 0u;
  if (mm0 & 0x00000001u) rv0.x = 0.f;
  if (mm0 & 0x00000100u) rv0.y = 0.f;
  if (mm0 & 0x00010000u) rv0.z = 0.f;
  if (mm0 & 0x01000000u) rv0.w = 0.f;
  if (mm1 & 0x00000001u) rv1.x = 0.f;
  if (mm1 & 0x00000100u) rv1.y = 0.f;
  if (mm1 & 0x00010000u) rv1.z = 0.f;
  if (mm1 & 0x01000000u) rv1.w = 0.f;
  if (mm2 & 0x00000001u) rv2.x = 0.f;
  if (mm2 & 0x00000100u) rv2.y = 0.f;
  if (mm2 & 0x00010000u) rv2.z = 0.f;
  if (mm2 & 0x01000000u) rv2.w = 0.f;

  // special case p==0 (clamped.at[0]): tid0-local registers
  int spec = 0; float delta = 0.f, val0 = 0.f;
  if (b==0 && tid==0 && !(mm0 & 1u)){
    float v0 = conf_data[0], v1 = conf_data[1];
    float r0 = rv0.x;                        // lse - v0 = true ce
    float r0p = r0 + v0 - v1;                // lse - v1 = ranking value
    delta = r0 - r0p;
    spec = 1;
    rv0.x = r0p; val0 = r0p;
  }

  // positive pass (identical iteration order; conf refetch is L2-hot)
  float ll=0.f, pc=0.f; int np=0;
  for (int p=tid;p<PP;p+=BTS){
    int mt = s_meta[p];
    if (mt & 1){
      np++;
      int n = mt>>1;
      int ct = (int)s_lab[n] + 1;
      const float* cp = conf_data + ((long)b*PP+p)*NC;
      float v0 = cp[0], vct = cp[ct];
      pc += s_val[p] + v0 - vct;             // lse - v[ct]
      float4 t = s_tr4[n];
      float4 prr = reinterpret_cast<const float4*>(priors)[p];
      float4 ld = reinterpret_cast<const float4*>(loc_data)[(long)b*PP+p];
      float g0 = ((t.x+t.z)*0.5f - prr.x)/(0.1f*prr.z);
      float g1 = ((t.y+t.w)*0.5f - prr.y)/(0.1f*prr.w);
      float g2 = __logf((t.z-t.x)/prr.z)/0.2f;
      float g3 = __logf((t.w-t.y)/prr.w)/0.2f;
      ll += sl1(ld.x-g0)+sl1(ld.y-g1)+sl1(ld.z-g2)+sl1(ld.w-g3);
    }
  }
  #pragma unroll
  for (int o=32;o;o>>=1){
    ll += __shfl_down(ll,o,64);
    pc += __shfl_down(pc,o,64);
    np += __shfl_down(np,o,64);
  }
  if (lane==0){ s_fa[wid]=ll; s_fb[wid]=pc; s_ia[wid]=np; }
  __syncthreads();
  if (tid==0){
    float a=0.f,c2=0.f; int ni=0;
    for (int w=0;w<NWS;w++){ a+=s_fa[w]; c2+=s_fb[w]; ni+=s_ia[w]; }
    s_rowll=a; s_rowpc=c2; s_npos=ni;
  }
  __syncthreads();
  const int num_pos = s_npos;
  int k = num_pos*3; if (k > PP-1) k = PP-1;

  float negsum = 0.f;
  if (k > 0){
    // k-th largest via binary search on float bits; DPP add + one LDS atomic per
    // wave + one broadcast read per iteration.
    unsigned lo=0u, hi=0x7f800000u;
    int it=0;
    while (lo < hi){
      unsigned mid = lo + ((hi - lo + 1u) >> 1);
      int c = (__float_as_uint(rv0.x)>=mid) + (__float_as_uint(rv0.y)>=mid)
            + (__float_as_uint(rv0.z)>=mid) + (__float_as_uint(rv0.w)>=mid)
            + (__float_as_uint(rv1.x)>=mid) + (__float_as_uint(rv1.y)>=mid)
            + (__float_as_uint(rv1.z)>=mid) + (__float_as_uint(rv1.w)>=mid)
            + (__float_as_uint(rv2.x)>=mid) + (__float_as_uint(rv2.y)>=mid)
            + (__float_as_uint(rv2.z)>=mid) + (__float_as_uint(rv2.w)>=mid);
      c = wave_sum64_lane63(c);
      if (lane==63) atomicAdd(&s_tot[it], c);
      __syncthreads();
      int tot = s_tot[it];
      if (tot >= k) lo = mid; else hi = mid - 1u;
      it++;                                   // <=31 iterations, s_tot[32] slots
    }
    const unsigned vstar = lo;

    int cg=0; float sg=0.f;
    #define ACC(x) if (__float_as_uint(x)>vstar){cg++;sg+=(x);}
    ACC(rv0.x) ACC(rv0.y) ACC(rv0.z) ACC(rv0.w)
    ACC(rv1.x) ACC(rv1.y) ACC(rv1.z) ACC(rv1.w)
    ACC(rv2.x) ACC(rv2.y) ACC(rv2.z) ACC(rv2.w)
    #undef ACC
    #pragma unroll
    for (int o=32;o;o>>=1){ cg += __shfl_down(cg,o,64); sg += __shfl_down(sg,o,64); }
    __syncthreads();
    if (lane==0){ s_ia[wid]=cg; s_fa[wid]=sg; }
    __syncthreads();
    if (tid==0){
      int cG=0; float sumG=0.f;
      for (int w=0;w<NWS;w++){ cG+=s_ia[w]; sumG+=s_fa[w]; }
      int tie = k - cG;                      // >=1; stable ties take lowest indices
      negsum = sumG + (float)tie * __uint_as_float(vstar);
      if (b==0 && spec && __float_as_uint(val0) >= vstar) negsum += delta;
    }
  }

  if (tid==0){
    rowres[b*4+0] = s_rowll;
    rowres[b*4+1] = s_rowpc + negsum;
    rowres[b*4+2] = (float)num_pos;
    __threadfence();
    int t = atomicAdd(ticket, 1);
    s_last = (t == Bn - 1) ? 1 : 0;
  }
  __syncthreads();

  if (s_last){
    __threadfence();
    float a0=0.f, a1=0.f, a2=0.f;
    for (int i=tid;i<Bn;i+=BTS){
      a0 += rowres[i*4+0]; a1 += rowres[i*4+1]; a2 += rowres[i*4+2];
    }
    #pragma unroll
    for (int o=32;o;o>>=1){
      a0 += __shfl_down(a0,o,64);
      a1 += __shfl_down(a1,o,64);
      a2 += __shfl_down(a2,o,64);
    }
    if (lane==0){ s_fa[wid]=a0; s_fb[wid]=a1; s_fc[wid]=a2; }
    __syncthreads();
    if (tid==0){
      float A0=0.f,A1=0.f,A2=0.f;
      for (int w=0;w<NWS;w++){ A0+=s_fa[w]; A1+=s_fb[w]; A2+=s_fc[w]; }
      out[0] = A0/A2;
      out[1] = A1/A2;
    }
  }
}

extern "C" void kernel_launch(void* const* d_in, const int* in_sizes, int n_in,
                              void* d_out, int out_size, void* d_ws, size_t ws_size,
                              hipStream_t stream) {
  const float* loc     = (const float*)d_in[0];
  const float* conf    = (const float*)d_in[1];
  const float* priors  = (const float*)d_in[2];
  const float* targets = (const float*)d_in[3];
  float* out = (float*)d_out;
  int B = in_sizes[0] / (PP*4);

  char* ws = (char*)d_ws;
  int*   ticket = (int*)ws;
  float* rowres = (float*)(ws + 64);
  unsigned long long* keys2 = (unsigned long long*)(ws + 4096);
  size_t off_rank = (4096 + (size_t)B*NCH*NB*8 + 255) & ~(size_t)255;
  float* rankneg = (float*)(ws + off_rank);
  unsigned char* metaa = (unsigned char*)(ws + off_rank + (size_t)B*PP*4);

  hipMemsetAsync(d_ws, 0, 64, stream);
  hipLaunchKernelGGL(mb_main,   dim3(B, NCH), dim3(BTH), 0, stream,
                     conf, priors, targets, rankneg, metaa, keys2);
  hipLaunchKernelGGL(mb_select, dim3(B), dim3(BTS), 0, stream,
                     loc, conf, priors, targets, rankneg, metaa, keys2,
                     rowres, ticket, out, B);
}